// Round 19
// baseline (154.088 us; speedup 1.0000x reference)
//
#include <hip/hip_runtime.h>
#include <math.h>

typedef unsigned short u16;
typedef unsigned int u32;
typedef __attribute__((ext_vector_type(8))) short bf16x8;
typedef __attribute__((ext_vector_type(4))) float f32x4;

#define SCALE_ 0.21022410381342864f   // 512^{-1/4}
#define EPS_ 1e-6f
#define RSQM_ 0.0625f                 // 1/sqrt(256)
#define L_ 8192
#define PL_OFF_ 131072                // PL = PH + 256 KiB (u16 elems)
#define KVL_OFF_ 524288               // KVtl = KVth + 1 MiB (u16 elems)

__device__ __forceinline__ float bf2f(u16 h) {
    return __uint_as_float(((u32)h) << 16);
}
__device__ __forceinline__ u32 cvtpk(float x0, float x1) {
    u32 w;
    asm("v_cvt_pk_bf16_f32 %0, %1, %2" : "=v"(w) : "v"(x0), "v"(x1));
    return w;
}
__device__ __forceinline__ void split_pk(float x0, float x1, u32& hw, u32& lw) {
    hw = cvtpk(x0, x1);
    float h0 = __uint_as_float(hw << 16);
    float h1 = __uint_as_float(hw & 0xffff0000u);
    lw = cvtpk(x0 - h0, x1 - h1);
}
__device__ __forceinline__ u32 okey(float x) {
    u32 b = __float_as_uint(x);
    return (b & 0x80000000u) ? ~b : (b | 0x80000000u);
}
__device__ __forceinline__ float odec(u32 k) {
    return (k & 0x80000000u) ? __uint_as_float(k & 0x7fffffffu) : __uint_as_float(~k);
}

#define GLDS16(gsrc, ldst) \
    __builtin_amdgcn_global_load_lds((__attribute__((address_space(1))) void*)(gsrc), \
                                     (__attribute__((address_space(3))) void*)(ldst), 16, 0, 0)

// P pre-scaled by SCALE_, hi/lo split; block 0 also zeroes bmax.
__global__ __launch_bounds__(256) void split_p(const float* __restrict__ P,
        u16* __restrict__ Ph, u16* __restrict__ Pl, u32* __restrict__ bmax) {
    if (blockIdx.x == 0 && threadIdx.x < 4) bmax[threadIdx.x] = 0u;
    int i = (blockIdx.x * 256 + threadIdx.x) * 2;
    u32 hw, lw;
    split_pk(P[i] * SCALE_, P[i + 1] * SCALE_, hw, lw);
    *reinterpret_cast<u32*>(&Ph[i]) = hw;
    *reinterpret_cast<u32*>(&Pl[i]) = lw;
}

// ---------------------------------------------------------------------------
// Fused dash GEMM, BK=64 (R16-proven). Tile 64x256, 256 thr / 4 waves,
// LDS 80 KB as two 32-wide halves, A fp32 prefetched 1 step ahead.
// Grid 1024: even=Q, odd=K.
// ---------------------------------------------------------------------------
__global__ __launch_bounds__(256) void dash_all(
        const float* __restrict__ Qg, const float* __restrict__ Kg,
        const u16* __restrict__ Bh_g,
        u16* __restrict__ QF, u16* __restrict__ KfT, float* __restrict__ ksump,
        u32* __restrict__ bmax) {
    __shared__ __align__(16) u16 Ah[2][64 * 32], Al[2][64 * 32];     // 16 KB
    __shared__ __align__(16) u16 Bh[2][256 * 32], Bl[2][256 * 32];   // 64 KB
    const int qpath = !(blockIdx.x & 1);
    const int tile = blockIdx.x >> 1;
    const float* __restrict__ X = qpath ? Qg : Kg;
    const int t = threadIdx.x, lane = t & 63;
    const int wid = t >> 6;                 // wave = 64-col (m) slice
    const int row0 = tile * 64;
    const int l15 = lane & 15, l4 = lane >> 4;
    const int sr = t >> 2;
    const int awz = sr * 32 + (((t & 3) ^ ((sr >> 1) & 3)) * 8);
    const int koff = (l4 ^ ((l15 >> 1) & 3)) * 8;
    float ss = 0.f;

    const float* xp = &X[(size_t)(row0 + sr) * 512 + (t & 3) * 8];
    const u16* bsrch[4];
#pragma unroll
    for (int it = 0; it < 4; ++it) {
        const int m = it * 64 + wid * 16 + (lane >> 2);
        const int swz = ((lane & 3) ^ ((m >> 1) & 3)) * 8;
        bsrch[it] = Bh_g + (size_t)m * 512 + swz;
    }

    f32x4 acc[4][4];
#pragma unroll
    for (int i = 0; i < 4; ++i)
#pragma unroll
        for (int j = 0; j < 4; ++j) acc[i][j] = (f32x4){0.f, 0.f, 0.f, 0.f};

    float4 v0 = *reinterpret_cast<const float4*>(xp);
    float4 v1 = *reinterpret_cast<const float4*>(xp + 4);
    float4 v2 = *reinterpret_cast<const float4*>(xp + 32);
    float4 v3 = *reinterpret_cast<const float4*>(xp + 36);

    for (int kt = 0; kt < 8; ++kt) {
        __syncthreads();
        {
#pragma unroll
            for (int it = 0; it < 4; ++it) {
                GLDS16(bsrch[it],                 &Bh[0][it * 2048 + wid * 512]);
                GLDS16(bsrch[it] + PL_OFF_,       &Bl[0][it * 2048 + wid * 512]);
                GLDS16(bsrch[it] + 32,            &Bh[1][it * 2048 + wid * 512]);
                GLDS16(bsrch[it] + 32 + PL_OFF_,  &Bl[1][it * 2048 + wid * 512]);
                bsrch[it] += 64;
            }
            float xs[8] = {v0.x, v0.y, v0.z, v0.w, v1.x, v1.y, v1.z, v1.w};
            float ys[8] = {v2.x, v2.y, v2.z, v2.w, v3.x, v3.y, v3.z, v3.w};
#pragma unroll
            for (int i = 0; i < 8; ++i) {
                ss = fmaf(xs[i], xs[i], ss);
                ss = fmaf(ys[i], ys[i], ss);
            }
            u32 hw[4], lw[4];
#pragma unroll
            for (int i = 0; i < 4; ++i) split_pk(xs[2 * i], xs[2 * i + 1], hw[i], lw[i]);
            *reinterpret_cast<uint4*>(&Ah[0][awz]) = make_uint4(hw[0], hw[1], hw[2], hw[3]);
            *reinterpret_cast<uint4*>(&Al[0][awz]) = make_uint4(lw[0], lw[1], lw[2], lw[3]);
#pragma unroll
            for (int i = 0; i < 4; ++i) split_pk(ys[2 * i], ys[2 * i + 1], hw[i], lw[i]);
            *reinterpret_cast<uint4*>(&Ah[1][awz]) = make_uint4(hw[0], hw[1], hw[2], hw[3]);
            *reinterpret_cast<uint4*>(&Al[1][awz]) = make_uint4(lw[0], lw[1], lw[2], lw[3]);
            xp = (kt < 7) ? xp + 64 : xp;
            v0 = *reinterpret_cast<const float4*>(xp);
            v1 = *reinterpret_cast<const float4*>(xp + 4);
            v2 = *reinterpret_cast<const float4*>(xp + 32);
            v3 = *reinterpret_cast<const float4*>(xp + 36);
        }
        __syncthreads();
#pragma unroll
        for (int h = 0; h < 2; ++h) {
            bf16x8 a_h[4], a_l[4];
#pragma unroll
            for (int mf = 0; mf < 4; ++mf) {
                int r = (mf * 16 + l15) * 32 + koff;
                a_h[mf] = *reinterpret_cast<const bf16x8*>(&Ah[h][r]);
                a_l[mf] = *reinterpret_cast<const bf16x8*>(&Al[h][r]);
            }
#pragma unroll
            for (int nf = 0; nf < 4; ++nf) {
                const int r = (wid * 64 + nf * 16 + l15) * 32 + koff;
                bf16x8 b_h = *reinterpret_cast<const bf16x8*>(&Bh[h][r]);
                bf16x8 b_l = *reinterpret_cast<const bf16x8*>(&Bl[h][r]);
#pragma unroll
                for (int mf = 0; mf < 4; ++mf) {
                    acc[mf][nf] = __builtin_amdgcn_mfma_f32_16x16x32_bf16(a_h[mf], b_h, acc[mf][nf], 0, 0, 0);
                    acc[mf][nf] = __builtin_amdgcn_mfma_f32_16x16x32_bf16(a_h[mf], b_l, acc[mf][nf], 0, 0, 0);
                    acc[mf][nf] = __builtin_amdgcn_mfma_f32_16x16x32_bf16(a_l[mf], b_h, acc[mf][nf], 0, 0, 0);
                }
            }
        }
    }
    __syncthreads();
    float* rmaxp = reinterpret_cast<float*>(&Ah[0][0]);   // [64][4]
    float* diagp = reinterpret_cast<float*>(&Al[0][0]);   // [64] + wmax[4] @64

    ss += __shfl_xor(ss, 1);
    ss += __shfl_xor(ss, 2);
    if ((t & 3) == 0) diagp[sr] = 0.5f * SCALE_ * SCALE_ * ss;

    if (qpath) {
        float rm[4][4];
#pragma unroll
        for (int mf = 0; mf < 4; ++mf)
#pragma unroll
            for (int r = 0; r < 4; ++r) {
                float v = fmaxf(fmaxf(acc[mf][0][r], acc[mf][1][r]),
                                fmaxf(acc[mf][2][r], acc[mf][3][r]));
#pragma unroll
                for (int off = 1; off < 16; off <<= 1) v = fmaxf(v, __shfl_xor(v, off));
                rm[mf][r] = v;
            }
        if (l15 == 0) {
#pragma unroll
            for (int mf = 0; mf < 4; ++mf)
#pragma unroll
                for (int r = 0; r < 4; ++r)
                    rmaxp[(mf * 16 + l4 * 4 + r) * 4 + wid] = rm[mf][r];
        }
        __syncthreads();
#pragma unroll
        for (int mf = 0; mf < 4; ++mf)
#pragma unroll
            for (int r = 0; r < 4; ++r) {
                const int rl = mf * 16 + l4 * 4 + r;
                float m4 = fmaxf(fmaxf(rmaxp[rl * 4 + 0], rmaxp[rl * 4 + 1]),
                                 fmaxf(rmaxp[rl * 4 + 2], rmaxp[rl * 4 + 3]));
                const float c = diagp[rl] + m4;
                float f0 = expf(acc[mf][0][r] - c) * RSQM_ + EPS_;
                float f1 = expf(acc[mf][1][r] - c) * RSQM_ + EPS_;
                float f2 = expf(acc[mf][2][r] - c) * RSQM_ + EPS_;
                float f3 = expf(acc[mf][3][r] - c) * RSQM_ + EPS_;
                u32 w01 = cvtpk(f0, f1), w23 = cvtpk(f2, f3);
                size_t o = (size_t)(row0 + rl) * 256 + wid * 64 + l15;
                QF[o]      = (u16)w01;
                QF[o + 16] = (u16)(w01 >> 16);
                QF[o + 32] = (u16)w23;
                QF[o + 48] = (u16)(w23 >> 16);
            }
    } else {
        __syncthreads();
        const int b = row0 >> 13;
        const int ll = row0 & 8191;
        float bm = -1e30f;
        float s[4] = {0.f, 0.f, 0.f, 0.f};
#pragma unroll
        for (int nf = 0; nf < 4; ++nf) {
            const size_t mb = ((size_t)(b * 256 + wid * 64 + nf * 16 + l15)) * 8192 + ll + l4 * 4;
#pragma unroll
            for (int mf = 0; mf < 4; ++mf) {
                float e0 = acc[mf][nf][0], e1 = acc[mf][nf][1];
                float e2 = acc[mf][nf][2], e3 = acc[mf][nf][3];
                bm = fmaxf(fmaxf(bm, fmaxf(e0, e1)), fmaxf(e2, e3));
                float x0 = expf(e0 - diagp[mf * 16 + l4 * 4 + 0]);
                float x1 = expf(e1 - diagp[mf * 16 + l4 * 4 + 1]);
                float x2 = expf(e2 - diagp[mf * 16 + l4 * 4 + 2]);
                float x3 = expf(e3 - diagp[mf * 16 + l4 * 4 + 3]);
                s[nf] += (x0 + x1) + (x2 + x3);
                uint2 w = make_uint2(cvtpk(x0, x1), cvtpk(x2, x3));
                *reinterpret_cast<uint2*>(&KfT[mb + mf * 16]) = w;
            }
        }
#pragma unroll
        for (int nf = 0; nf < 4; ++nf) {
            s[nf] += __shfl_xor(s[nf], 16);
            s[nf] += __shfl_xor(s[nf], 32);
        }
        if (l4 == 0) {
#pragma unroll
            for (int nf = 0; nf < 4; ++nf)
                ksump[tile * 256 + wid * 64 + nf * 16 + l15] = s[nf];
        }
#pragma unroll
        for (int off = 1; off < 64; off <<= 1) bm = fmaxf(bm, __shfl_xor(bm, off));
        if (lane == 0) diagp[64 + wid] = bm;
        __syncthreads();
        if (t == 0) {
            float m = fmaxf(fmaxf(diagp[64], diagp[65]), fmaxf(diagp[66], diagp[67]));
            atomicMax(&bmax[b], okey(m));
        }
    }
}

// Ksum_true[b][m] = e^{-bmax}*sum + L*EPS. WIDE: 1 wave per (b,m) output.
__global__ __launch_bounds__(256) void ksum_red(const float* __restrict__ ksump,
        const u32* __restrict__ bmax, float* __restrict__ KsumT) {
    const int wid = threadIdx.x >> 6, lane = threadIdx.x & 63;
    const int o = blockIdx.x * 4 + wid;         // 0..1023 = b*256+m
    const int b = o >> 8, m = o & 255;
    float s = ksump[(size_t)(b * 128 + lane) * 256 + m]
            + ksump[(size_t)(b * 128 + 64 + lane) * 256 + m];
#pragma unroll
    for (int off = 1; off < 64; off <<= 1) s += __shfl_xor(s, off);
    if (lane == 0) {
        const float g = expf(-odec(bmax[b]));
        KsumT[o] = g * s + (float)L_ * EPS_;
    }
}

// ---------------------------------------------------------------------------
// KV split-K GEMM with FUSED V transpose (R18-proven). BK=64, 8 steps.
// Tile 128x128, 256 thr / 4 waves, LDS 32 KB, grid 512.
// ---------------------------------------------------------------------------
__global__ __launch_bounds__(256) void kv_mfma(
        const u16* __restrict__ KfT, const float* __restrict__ V,
        float* __restrict__ kvp, float* __restrict__ vsump) {
    int o = (blockIdx.x & 7) * 64 + (blockIdx.x >> 3);
    const int dt = o & 3, mt = (o >> 2) & 1, ch = (o >> 3) & 15, b = o >> 7;
    const u16* Ag = KfT + ((size_t)(b * 256 + mt * 128)) * 8192 + ch * 512;
    const float* Vg = V + ((size_t)(b * 8192 + ch * 512)) * 512 + dt * 128;
    __shared__ __align__(16) u16 A_[2][128 * 32], B_[2][128 * 32];
    const int t = threadIdx.x, lane = t & 63;
    const int wid = t >> 6, wr = wid >> 1, wc = wid & 1;
    const int l15 = lane & 15, l4 = lane >> 4;
    const int koff = (l4 ^ ((l15 >> 1) & 3)) * 8;
    const u16* asrc[2];
#pragma unroll
    for (int it = 0; it < 2; ++it) {
        const int row = it * 64 + wid * 16 + (lane >> 2);
        const int swz = ((lane & 3) ^ ((row >> 1) & 3)) * 8;
        asrc[it] = Ag + (size_t)row * 8192 + swz;
    }
    const int dq = t >> 3;
    const int lpb = (t & 7) * 2;
    float vs[4] = {0.f, 0.f, 0.f, 0.f};

    f32x4 acc[4][4];
#pragma unroll
    for (int i = 0; i < 4; ++i)
#pragma unroll
        for (int j = 0; j < 4; ++j) acc[i][j] = (f32x4){0.f, 0.f, 0.f, 0.f};

    for (int kt = 0; kt < 8; ++kt) {
        __syncthreads();
#pragma unroll
        for (int it = 0; it < 2; ++it) {
            GLDS16(asrc[it],      &A_[0][it * 2048 + wid * 512]);
            GLDS16(asrc[it] + 32, &A_[1][it * 2048 + wid * 512]);
            asrc[it] += 64;
        }
#pragma unroll
        for (int h = 0; h < 2; ++h)
#pragma unroll
            for (int j = 0; j < 2; ++j) {
                const int lp = lpb + j;
                const int l = kt * 64 + h * 32 + lp * 2;
                const float* vp = Vg + (size_t)l * 512 + dq * 4;
                float4 va = *reinterpret_cast<const float4*>(vp);
                float4 vb = *reinterpret_cast<const float4*>(vp + 512);
                const int lo = lp * 2;
                const int lblk = lo >> 3, lin = lo & 7;
                float av[4] = {va.x, va.y, va.z, va.w};
                float bv[4] = {vb.x, vb.y, vb.z, vb.w};
#pragma unroll
                for (int d = 0; d < 4; ++d) {
                    const int drow = dq * 4 + d;
                    const int ls = (lblk ^ ((drow >> 1) & 3)) * 8 + lin;
                    *reinterpret_cast<u32*>(&B_[h][drow * 32 + ls]) = cvtpk(av[d], bv[d]);
                    vs[d] += av[d] + bv[d];
                }
            }
        __syncthreads();
#pragma unroll
        for (int h = 0; h < 2; ++h) {
            bf16x8 a[4];
#pragma unroll
            for (int mf = 0; mf < 4; ++mf)
                a[mf] = *reinterpret_cast<const bf16x8*>(&A_[h][(wr * 64 + mf * 16 + l15) * 32 + koff]);
#pragma unroll
            for (int nf = 0; nf < 4; ++nf) {
                bf16x8 bb = *reinterpret_cast<const bf16x8*>(&B_[h][(wc * 64 + nf * 16 + l15) * 32 + koff]);
#pragma unroll
                for (int mf = 0; mf < 4; ++mf)
                    acc[mf][nf] = __builtin_amdgcn_mfma_f32_16x16x32_bf16(a[mf], bb, acc[mf][nf], 0, 0, 0);
            }
        }
    }
#pragma unroll
    for (int d = 0; d < 4; ++d) {
        vs[d] += __shfl_xor(vs[d], 1);
        vs[d] += __shfl_xor(vs[d], 2);
        vs[d] += __shfl_xor(vs[d], 4);
    }
    if (mt == 0 && (t & 7) == 0) {
        float4 w = make_float4(vs[0], vs[1], vs[2], vs[3]);
        *reinterpret_cast<float4*>(&vsump[(size_t)ch * 2048 + b * 512 + dt * 128 + dq * 4]) = w;
    }
#pragma unroll
    for (int mf = 0; mf < 4; ++mf)
#pragma unroll
        for (int r = 0; r < 4; ++r) {
            size_t oo = ((size_t)(ch * 4 + b) * 256 + mt * 128 + wr * 64 + mf * 16 + l4 * 4 + r) * 512
                        + dt * 128 + wc * 64;
#pragma unroll
            for (int nf = 0; nf < 4; ++nf)
                kvp[oo + nf * 16 + l15] = acc[mf][nf][r];
        }
}

// Vsum[b][d] = sum over 16 chunks of vsump[ch][b*512+d]
__global__ __launch_bounds__(256) void vsum_red(const float* __restrict__ vsump,
        float* __restrict__ Vsum) {
    const int o = blockIdx.x * 256 + threadIdx.x;   // 0..2047
    float s = 0.f;
#pragma unroll
    for (int c = 0; c < 16; ++c) s += vsump[(size_t)c * 2048 + o];
    Vsum[o] = s;
}

// reduce 16 chunks + KV_adj = g*KV + EPS*Vsum, split hi/lo, transpose -> KVt [b][d][m]
__global__ __launch_bounds__(256) void kv_fix(const float* __restrict__ kvp,
        const u32* __restrict__ bmax, const float* __restrict__ Vsum,
        u16* __restrict__ KVth, u16* __restrict__ KVtl) {
    const int dt = blockIdx.x & 7, mt = (blockIdx.x >> 3) & 3, b = blockIdx.x >> 5;
    const int m0 = mt * 64, d0 = dt * 64;
    __shared__ u16 Th[64][72], Tl[64][72];
    const int t = threadIdx.x, mloc = t >> 2, c0 = (t & 3) * 16;
    float s[16];
#pragma unroll
    for (int j = 0; j < 16; ++j) s[j] = 0.f;
    for (int c = 0; c < 16; ++c) {
        size_t base = ((size_t)(c * 4 + b) * 256 + m0 + mloc) * 512 + d0 + c0;
#pragma unroll
        for (int ii = 0; ii < 4; ++ii) {
            float4 v = *reinterpret_cast<const float4*>(&kvp[base + ii * 4]);
            s[ii * 4 + 0] += v.x; s[ii * 4 + 1] += v.y;
            s[ii * 4 + 2] += v.z; s[ii * 4 + 3] += v.w;
        }
    }
    const float g = expf(-odec(bmax[b]));
#pragma unroll
    for (int j = 0; j < 16; j += 2) {
        float v0 = g * s[j]     + EPS_ * Vsum[b * 512 + d0 + c0 + j];
        float v1 = g * s[j + 1] + EPS_ * Vsum[b * 512 + d0 + c0 + j + 1];
        u32 hw, lw; split_pk(v0, v1, hw, lw);
        *reinterpret_cast<u32*>(&Th[mloc][c0 + j]) = hw;
        *reinterpret_cast<u32*>(&Tl[mloc][c0 + j]) = lw;
    }
    __syncthreads();
    const int dloc = t >> 2, mc = (t & 3) * 16;
    size_t ob = ((size_t)(b * 512 + d0 + dloc)) * 256 + m0 + mc;
    u32 wh[8], wl[8];
#pragma unroll
    for (int j = 0; j < 8; ++j) {
        wh[j] = (u32)Th[mc + 2 * j][dloc] | ((u32)Th[mc + 2 * j + 1][dloc] << 16);
        wl[j] = (u32)Tl[mc + 2 * j][dloc] | ((u32)Tl[mc + 2 * j + 1][dloc] << 16);
    }
    reinterpret_cast<uint4*>(&KVth[ob])[0] = make_uint4(wh[0], wh[1], wh[2], wh[3]);
    reinterpret_cast<uint4*>(&KVth[ob])[1] = make_uint4(wh[4], wh[5], wh[6], wh[7]);
    reinterpret_cast<uint4*>(&KVtl[ob])[0] = make_uint4(wl[0], wl[1], wl[2], wl[3]);
    reinterpret_cast<uint4*>(&KVtl[ob])[1] = make_uint4(wl[4], wl[5], wl[6], wl[7]);
}

// ---------------------------------------------------------------------------
// out GEMM with FUSED Z (z_kernel deleted). BK=64, 4 K-steps. While A
// fragments (= QF rows) are in registers, accumulate zacc[mf] = QF.KsumT
// partials (logical k of fragment a[mf] = kt*64 + h*32 + l4*8 + j; the XOR
// swizzle cancels for A rows since mf*16 % 8 == 0). Reduce over l4 via shfl,
// stage Z through LDS, apply in C-write. Tile 128x128, 256 thr, grid 1024.
// ---------------------------------------------------------------------------
__global__ __launch_bounds__(256) void out_mfma(
        const u16* __restrict__ QF, const u16* __restrict__ KVth,
        const float* __restrict__ KsumT, float* __restrict__ out) {
    int o = (blockIdx.x & 7) * 128 + (blockIdx.x >> 3);
    const int dt = o & 3, rt = o >> 2;
    const int row0 = rt * 128, b = row0 >> 13;
    const u16* Ag = QF + (size_t)row0 * 256;
    const u16* Bh_g = KVth + ((size_t)(b * 512 + dt * 128)) * 256;
    const float* ksb = KsumT + b * 256;
    __shared__ __align__(16) u16 A_[2][128 * 32], Bh_[2][128 * 32], Bl_[2][128 * 32];
    const int t = threadIdx.x, lane = t & 63;
    const int wid = t >> 6, wr = wid >> 1, wc = wid & 1;
    const int l15 = lane & 15, l4 = lane >> 4;
    const int koff = (l4 ^ ((l15 >> 1) & 3)) * 8;
    const u16* asrc[2];
    const u16* bhsrc[2];
#pragma unroll
    for (int it = 0; it < 2; ++it) {
        const int row = it * 64 + wid * 16 + (lane >> 2);
        const int swz = ((lane & 3) ^ ((row >> 1) & 3)) * 8;
        asrc[it]  = Ag + (size_t)row * 256 + swz;
        bhsrc[it] = Bh_g + (size_t)row * 256 + swz;
    }
    f32x4 acc[4][4];
#pragma unroll
    for (int i = 0; i < 4; ++i)
#pragma unroll
        for (int j = 0; j < 4; ++j) acc[i][j] = (f32x4){0.f, 0.f, 0.f, 0.f};
    float zacc[4] = {0.f, 0.f, 0.f, 0.f};

    for (int kt = 0; kt < 4; ++kt) {
        __syncthreads();
#pragma unroll
        for (int it = 0; it < 2; ++it) {
            GLDS16(asrc[it],                  &A_[0][it * 2048 + wid * 512]);
            GLDS16(asrc[it] + 32,             &A_[1][it * 2048 + wid * 512]);
            GLDS16(bhsrc[it],                 &Bh_[0][it * 2048 + wid * 512]);
            GLDS16(bhsrc[it] + 32,            &Bh_[1][it * 2048 + wid * 512]);
            GLDS16(bhsrc[it] + KVL_OFF_,      &Bl_[0][it * 2048 + wid * 512]);
            GLDS16(bhsrc[it] + 32 + KVL_OFF_, &Bl_[1][it * 2048 + wid * 512]);
            asrc[it] += 64; bhsrc[it] += 64;
        }
        __syncthreads();
#pragma unroll
        for (int h = 0; h < 2; ++h) {
            bf16x8 a[4];
#pragma unroll
            for (int mf = 0; mf < 4; ++mf)
                a[mf] = *reinterpret_cast<const bf16x8*>(&A_[h][(wr * 64 + mf * 16 + l15) * 32 + koff]);
            // Z partials: logical k of a[mf][j] is kt*64 + h*32 + l4*8 + j
            {
                const int kb = kt * 64 + h * 32 + l4 * 8;
                float4 k0 = *reinterpret_cast<const float4*>(&ksb[kb]);
                float4 k1 = *reinterpret_cast<const float4*>(&ksb[kb + 4]);
                float kk[8] = {k0.x, k0.y, k0.z, k0.w, k1.x, k1.y, k1.z, k1.w};
#pragma unroll
                for (int mf = 0; mf < 4; ++mf)
#pragma unroll
                    for (int j = 0; j < 8; ++j)
                        zacc[mf] = fmaf(bf2f((u16)a[mf][j]), kk[j], zacc[mf]);
            }
#pragma unroll
            for (int nf = 0; nf < 4; ++nf) {
                const int r = (wc * 64 + nf * 16 + l15) * 32 + koff;
                bf16x8 bh = *reinterpret_cast<const bf16x8*>(&Bh_[h][r]);
                bf16x8 bl = *reinterpret_cast<const bf16x8*>(&Bl_[h][r]);
#pragma unroll
                for (int mf = 0; mf < 4; ++mf) {
                    acc[mf][nf] = __builtin_amdgcn_mfma_f32_16x16x32_bf16(a[mf], bh, acc[mf][nf], 0, 0, 0);
                    acc[mf][nf] = __builtin_amdgcn_mfma_f32_16x16x32_bf16(a[mf], bl, acc[mf][nf], 0, 0, 0);
                }
            }
        }
    }
    // finish Z: reduce over l4 (lane bits 4..5), invert, stage through LDS
    __syncthreads();
    float* zl = reinterpret_cast<float*>(&A_[0][0]);   // 128 floats
#pragma unroll
    for (int mf = 0; mf < 4; ++mf) {
        float s = zacc[mf];
        s += __shfl_xor(s, 16);
        s += __shfl_xor(s, 32);
        if (wc == 0 && l4 == 0) zl[wr * 64 + mf * 16 + l15] = 1.f / (s + EPS_);
    }
    __syncthreads();
#pragma unroll
    for (int mf = 0; mf < 4; ++mf)
#pragma unroll
        for (int r = 0; r < 4; ++r) {
            const int rl = wr * 64 + mf * 16 + l4 * 4 + r;
            const float z = zl[rl];
            const int row = row0 + rl;
#pragma unroll
            for (int nf = 0; nf < 4; ++nf)
                out[(size_t)row * 512 + dt * 128 + wc * 64 + nf * 16 + l15] = acc[mf][nf][r] * z;
        }
}

extern "C" void kernel_launch(void* const* d_in, const int* in_sizes, int n_in,
                              void* d_out, int out_size, void* d_ws, size_t ws_size,
                              hipStream_t stream) {
    const float* Q = (const float*)d_in[0];
    const float* K = (const float*)d_in[1];
    const float* V = (const float*)d_in[2];
    const float* P = (const float*)d_in[3];
    float* out = (float*)d_out;
    char* ws = (char*)d_ws;

    u16*   QF    = (u16*)(ws + 0);             // 16 MiB
    u16*   KfT   = (u16*)(ws + 16777216);      // 16 MiB
    float* kvp   = (float*)(ws + 33554432);    // 32 MiB
    u16*   KVth  = (u16*)(ws + 67108864);      // 1 MiB
    u16*   KVtl  = (u16*)(ws + 68157440);      // 1 MiB (= KVth + 524288 elems)
    u16*   PH    = (u16*)(ws + 69206016);      // 256 KiB
    u16*   PL    = (u16*)(ws + 69468160);      // 256 KiB (= PH + 131072 elems)
    float* ksump = (float*)(ws + 69730304);    // 512 KiB
    float* vsump = (float*)(ws + 70254592);    // 128 KiB (16 ch x 2048)
    float* KsumT = (float*)(ws + 70385664);    // 4 KiB
    float* Vsum  = (float*)(ws + 70389760);    // 8 KiB
    u32*   bmax  = (u32*)(ws + 70529024);      // 16 B

    split_p<<<256, 256, 0, stream>>>(P, PH, PL, bmax);
    dash_all<<<1024, 256, 0, stream>>>(Q, K, PH, QF, KfT, ksump, bmax);
    ksum_red<<<256, 256, 0, stream>>>(ksump, bmax, KsumT);
    kv_mfma<<<512, 256, 0, stream>>>(KfT, V, kvp, vsump);
    vsum_red<<<8, 256, 0, stream>>>(vsump, Vsum);
    kv_fix<<<128, 256, 0, stream>>>(kvp, bmax, Vsum, KVth, KVtl);
    out_mfma<<<1024, 256, 0, stream>>>(QF, KVth, KsumT, out);
}

// Round 20
// 151.379 us; speedup vs baseline: 1.0179x; 1.0179x over previous
//
#include <hip/hip_runtime.h>
#include <math.h>

typedef unsigned short u16;
typedef unsigned int u32;
typedef __attribute__((ext_vector_type(8))) short bf16x8;
typedef __attribute__((ext_vector_type(4))) float f32x4;

#define SCALE_ 0.21022410381342864f   // 512^{-1/4}
#define EPS_ 1e-6f
#define RSQM_ 0.0625f                 // 1/sqrt(256)
#define L_ 8192
#define PL_OFF_ 131072                // PL = PH + 256 KiB (u16 elems)
#define KVL_OFF_ 524288               // KVtl = KVth + 1 MiB (u16 elems)

__device__ __forceinline__ float bf2f(u16 h) {
    return __uint_as_float(((u32)h) << 16);
}
__device__ __forceinline__ u32 cvtpk(float x0, float x1) {
    u32 w;
    asm("v_cvt_pk_bf16_f32 %0, %1, %2" : "=v"(w) : "v"(x0), "v"(x1));
    return w;
}
__device__ __forceinline__ void split_pk(float x0, float x1, u32& hw, u32& lw) {
    hw = cvtpk(x0, x1);
    float h0 = __uint_as_float(hw << 16);
    float h1 = __uint_as_float(hw & 0xffff0000u);
    lw = cvtpk(x0 - h0, x1 - h1);
}
__device__ __forceinline__ u32 okey(float x) {
    u32 b = __float_as_uint(x);
    return (b & 0x80000000u) ? ~b : (b | 0x80000000u);
}
__device__ __forceinline__ float odec(u32 k) {
    return (k & 0x80000000u) ? __uint_as_float(k & 0x7fffffffu) : __uint_as_float(~k);
}

#define GLDS16(gsrc, ldst) \
    __builtin_amdgcn_global_load_lds((__attribute__((address_space(1))) void*)(gsrc), \
                                     (__attribute__((address_space(3))) void*)(ldst), 16, 0, 0)

// P pre-scaled by SCALE_, hi/lo split; block 0 also zeroes bmax.
__global__ __launch_bounds__(256) void split_p(const float* __restrict__ P,
        u16* __restrict__ Ph, u16* __restrict__ Pl, u32* __restrict__ bmax) {
    if (blockIdx.x == 0 && threadIdx.x < 4) bmax[threadIdx.x] = 0u;
    int i = (blockIdx.x * 256 + threadIdx.x) * 2;
    u32 hw, lw;
    split_pk(P[i] * SCALE_, P[i + 1] * SCALE_, hw, lw);
    *reinterpret_cast<u32*>(&Ph[i]) = hw;
    *reinterpret_cast<u32*>(&Pl[i]) = lw;
}

// ---------------------------------------------------------------------------
// Fused dash GEMM, BK=64 (R16-proven). Tile 64x256, 256 thr / 4 waves,
// LDS 80 KB as two 32-wide halves, A fp32 prefetched 1 step ahead.
// Grid 1024: even=Q, odd=K.
// ---------------------------------------------------------------------------
__global__ __launch_bounds__(256) void dash_all(
        const float* __restrict__ Qg, const float* __restrict__ Kg,
        const u16* __restrict__ Bh_g,
        u16* __restrict__ QF, u16* __restrict__ KfT, float* __restrict__ ksump,
        u32* __restrict__ bmax) {
    __shared__ __align__(16) u16 Ah[2][64 * 32], Al[2][64 * 32];     // 16 KB
    __shared__ __align__(16) u16 Bh[2][256 * 32], Bl[2][256 * 32];   // 64 KB
    const int qpath = !(blockIdx.x & 1);
    const int tile = blockIdx.x >> 1;
    const float* __restrict__ X = qpath ? Qg : Kg;
    const int t = threadIdx.x, lane = t & 63;
    const int wid = t >> 6;                 // wave = 64-col (m) slice
    const int row0 = tile * 64;
    const int l15 = lane & 15, l4 = lane >> 4;
    const int sr = t >> 2;
    const int awz = sr * 32 + (((t & 3) ^ ((sr >> 1) & 3)) * 8);
    const int koff = (l4 ^ ((l15 >> 1) & 3)) * 8;
    float ss = 0.f;

    const float* xp = &X[(size_t)(row0 + sr) * 512 + (t & 3) * 8];
    const u16* bsrch[4];
#pragma unroll
    for (int it = 0; it < 4; ++it) {
        const int m = it * 64 + wid * 16 + (lane >> 2);
        const int swz = ((lane & 3) ^ ((m >> 1) & 3)) * 8;
        bsrch[it] = Bh_g + (size_t)m * 512 + swz;
    }

    f32x4 acc[4][4];
#pragma unroll
    for (int i = 0; i < 4; ++i)
#pragma unroll
        for (int j = 0; j < 4; ++j) acc[i][j] = (f32x4){0.f, 0.f, 0.f, 0.f};

    float4 v0 = *reinterpret_cast<const float4*>(xp);
    float4 v1 = *reinterpret_cast<const float4*>(xp + 4);
    float4 v2 = *reinterpret_cast<const float4*>(xp + 32);
    float4 v3 = *reinterpret_cast<const float4*>(xp + 36);

    for (int kt = 0; kt < 8; ++kt) {
        __syncthreads();
        {
#pragma unroll
            for (int it = 0; it < 4; ++it) {
                GLDS16(bsrch[it],                 &Bh[0][it * 2048 + wid * 512]);
                GLDS16(bsrch[it] + PL_OFF_,       &Bl[0][it * 2048 + wid * 512]);
                GLDS16(bsrch[it] + 32,            &Bh[1][it * 2048 + wid * 512]);
                GLDS16(bsrch[it] + 32 + PL_OFF_,  &Bl[1][it * 2048 + wid * 512]);
                bsrch[it] += 64;
            }
            float xs[8] = {v0.x, v0.y, v0.z, v0.w, v1.x, v1.y, v1.z, v1.w};
            float ys[8] = {v2.x, v2.y, v2.z, v2.w, v3.x, v3.y, v3.z, v3.w};
#pragma unroll
            for (int i = 0; i < 8; ++i) {
                ss = fmaf(xs[i], xs[i], ss);
                ss = fmaf(ys[i], ys[i], ss);
            }
            u32 hw[4], lw[4];
#pragma unroll
            for (int i = 0; i < 4; ++i) split_pk(xs[2 * i], xs[2 * i + 1], hw[i], lw[i]);
            *reinterpret_cast<uint4*>(&Ah[0][awz]) = make_uint4(hw[0], hw[1], hw[2], hw[3]);
            *reinterpret_cast<uint4*>(&Al[0][awz]) = make_uint4(lw[0], lw[1], lw[2], lw[3]);
#pragma unroll
            for (int i = 0; i < 4; ++i) split_pk(ys[2 * i], ys[2 * i + 1], hw[i], lw[i]);
            *reinterpret_cast<uint4*>(&Ah[1][awz]) = make_uint4(hw[0], hw[1], hw[2], hw[3]);
            *reinterpret_cast<uint4*>(&Al[1][awz]) = make_uint4(lw[0], lw[1], lw[2], lw[3]);
            xp = (kt < 7) ? xp + 64 : xp;
            v0 = *reinterpret_cast<const float4*>(xp);
            v1 = *reinterpret_cast<const float4*>(xp + 4);
            v2 = *reinterpret_cast<const float4*>(xp + 32);
            v3 = *reinterpret_cast<const float4*>(xp + 36);
        }
        __syncthreads();
#pragma unroll
        for (int h = 0; h < 2; ++h) {
            bf16x8 a_h[4], a_l[4];
#pragma unroll
            for (int mf = 0; mf < 4; ++mf) {
                int r = (mf * 16 + l15) * 32 + koff;
                a_h[mf] = *reinterpret_cast<const bf16x8*>(&Ah[h][r]);
                a_l[mf] = *reinterpret_cast<const bf16x8*>(&Al[h][r]);
            }
#pragma unroll
            for (int nf = 0; nf < 4; ++nf) {
                const int r = (wid * 64 + nf * 16 + l15) * 32 + koff;
                bf16x8 b_h = *reinterpret_cast<const bf16x8*>(&Bh[h][r]);
                bf16x8 b_l = *reinterpret_cast<const bf16x8*>(&Bl[h][r]);
#pragma unroll
                for (int mf = 0; mf < 4; ++mf) {
                    acc[mf][nf] = __builtin_amdgcn_mfma_f32_16x16x32_bf16(a_h[mf], b_h, acc[mf][nf], 0, 0, 0);
                    acc[mf][nf] = __builtin_amdgcn_mfma_f32_16x16x32_bf16(a_h[mf], b_l, acc[mf][nf], 0, 0, 0);
                    acc[mf][nf] = __builtin_amdgcn_mfma_f32_16x16x32_bf16(a_l[mf], b_h, acc[mf][nf], 0, 0, 0);
                }
            }
        }
    }
    __syncthreads();
    float* rmaxp = reinterpret_cast<float*>(&Ah[0][0]);   // [64][4]
    float* diagp = reinterpret_cast<float*>(&Al[0][0]);   // [64] + wmax[4] @64

    ss += __shfl_xor(ss, 1);
    ss += __shfl_xor(ss, 2);
    if ((t & 3) == 0) diagp[sr] = 0.5f * SCALE_ * SCALE_ * ss;

    if (qpath) {
        float rm[4][4];
#pragma unroll
        for (int mf = 0; mf < 4; ++mf)
#pragma unroll
            for (int r = 0; r < 4; ++r) {
                float v = fmaxf(fmaxf(acc[mf][0][r], acc[mf][1][r]),
                                fmaxf(acc[mf][2][r], acc[mf][3][r]));
#pragma unroll
                for (int off = 1; off < 16; off <<= 1) v = fmaxf(v, __shfl_xor(v, off));
                rm[mf][r] = v;
            }
        if (l15 == 0) {
#pragma unroll
            for (int mf = 0; mf < 4; ++mf)
#pragma unroll
                for (int r = 0; r < 4; ++r)
                    rmaxp[(mf * 16 + l4 * 4 + r) * 4 + wid] = rm[mf][r];
        }
        __syncthreads();
#pragma unroll
        for (int mf = 0; mf < 4; ++mf)
#pragma unroll
            for (int r = 0; r < 4; ++r) {
                const int rl = mf * 16 + l4 * 4 + r;
                float m4 = fmaxf(fmaxf(rmaxp[rl * 4 + 0], rmaxp[rl * 4 + 1]),
                                 fmaxf(rmaxp[rl * 4 + 2], rmaxp[rl * 4 + 3]));
                const float c = diagp[rl] + m4;
                float f0 = expf(acc[mf][0][r] - c) * RSQM_ + EPS_;
                float f1 = expf(acc[mf][1][r] - c) * RSQM_ + EPS_;
                float f2 = expf(acc[mf][2][r] - c) * RSQM_ + EPS_;
                float f3 = expf(acc[mf][3][r] - c) * RSQM_ + EPS_;
                u32 w01 = cvtpk(f0, f1), w23 = cvtpk(f2, f3);
                size_t o = (size_t)(row0 + rl) * 256 + wid * 64 + l15;
                QF[o]      = (u16)w01;
                QF[o + 16] = (u16)(w01 >> 16);
                QF[o + 32] = (u16)w23;
                QF[o + 48] = (u16)(w23 >> 16);
            }
    } else {
        __syncthreads();
        const int b = row0 >> 13;
        const int ll = row0 & 8191;
        float bm = -1e30f;
        float s[4] = {0.f, 0.f, 0.f, 0.f};
#pragma unroll
        for (int nf = 0; nf < 4; ++nf) {
            const size_t mb = ((size_t)(b * 256 + wid * 64 + nf * 16 + l15)) * 8192 + ll + l4 * 4;
#pragma unroll
            for (int mf = 0; mf < 4; ++mf) {
                float e0 = acc[mf][nf][0], e1 = acc[mf][nf][1];
                float e2 = acc[mf][nf][2], e3 = acc[mf][nf][3];
                bm = fmaxf(fmaxf(bm, fmaxf(e0, e1)), fmaxf(e2, e3));
                float x0 = expf(e0 - diagp[mf * 16 + l4 * 4 + 0]);
                float x1 = expf(e1 - diagp[mf * 16 + l4 * 4 + 1]);
                float x2 = expf(e2 - diagp[mf * 16 + l4 * 4 + 2]);
                float x3 = expf(e3 - diagp[mf * 16 + l4 * 4 + 3]);
                s[nf] += (x0 + x1) + (x2 + x3);
                uint2 w = make_uint2(cvtpk(x0, x1), cvtpk(x2, x3));
                *reinterpret_cast<uint2*>(&KfT[mb + mf * 16]) = w;
            }
        }
#pragma unroll
        for (int nf = 0; nf < 4; ++nf) {
            s[nf] += __shfl_xor(s[nf], 16);
            s[nf] += __shfl_xor(s[nf], 32);
        }
        if (l4 == 0) {
#pragma unroll
            for (int nf = 0; nf < 4; ++nf)
                ksump[tile * 256 + wid * 64 + nf * 16 + l15] = s[nf];
        }
#pragma unroll
        for (int off = 1; off < 64; off <<= 1) bm = fmaxf(bm, __shfl_xor(bm, off));
        if (lane == 0) diagp[64 + wid] = bm;
        __syncthreads();
        if (t == 0) {
            float m = fmaxf(fmaxf(diagp[64], diagp[65]), fmaxf(diagp[66], diagp[67]));
            atomicMax(&bmax[b], okey(m));
        }
    }
}

// Ksum_true[b][m] = e^{-bmax}*sum + L*EPS. WIDE: 1 wave per (b,m) output.
__global__ __launch_bounds__(256) void ksum_red(const float* __restrict__ ksump,
        const u32* __restrict__ bmax, float* __restrict__ KsumT) {
    const int wid = threadIdx.x >> 6, lane = threadIdx.x & 63;
    const int o = blockIdx.x * 4 + wid;         // 0..1023 = b*256+m
    const int b = o >> 8, m = o & 255;
    float s = ksump[(size_t)(b * 128 + lane) * 256 + m]
            + ksump[(size_t)(b * 128 + 64 + lane) * 256 + m];
#pragma unroll
    for (int off = 1; off < 64; off <<= 1) s += __shfl_xor(s, off);
    if (lane == 0) {
        const float g = expf(-odec(bmax[b]));
        KsumT[o] = g * s + (float)L_ * EPS_;
    }
}

// ---------------------------------------------------------------------------
// KV split-K GEMM with FUSED V transpose (R18-proven). BK=64, 8 steps.
// Tile 128x128, 256 thr / 4 waves, LDS 32 KB, grid 512.
// ---------------------------------------------------------------------------
__global__ __launch_bounds__(256) void kv_mfma(
        const u16* __restrict__ KfT, const float* __restrict__ V,
        float* __restrict__ kvp, float* __restrict__ vsump) {
    int o = (blockIdx.x & 7) * 64 + (blockIdx.x >> 3);
    const int dt = o & 3, mt = (o >> 2) & 1, ch = (o >> 3) & 15, b = o >> 7;
    const u16* Ag = KfT + ((size_t)(b * 256 + mt * 128)) * 8192 + ch * 512;
    const float* Vg = V + ((size_t)(b * 8192 + ch * 512)) * 512 + dt * 128;
    __shared__ __align__(16) u16 A_[2][128 * 32], B_[2][128 * 32];
    const int t = threadIdx.x, lane = t & 63;
    const int wid = t >> 6, wr = wid >> 1, wc = wid & 1;
    const int l15 = lane & 15, l4 = lane >> 4;
    const int koff = (l4 ^ ((l15 >> 1) & 3)) * 8;
    const u16* asrc[2];
#pragma unroll
    for (int it = 0; it < 2; ++it) {
        const int row = it * 64 + wid * 16 + (lane >> 2);
        const int swz = ((lane & 3) ^ ((row >> 1) & 3)) * 8;
        asrc[it] = Ag + (size_t)row * 8192 + swz;
    }
    const int dq = t >> 3;
    const int lpb = (t & 7) * 2;
    float vs[4] = {0.f, 0.f, 0.f, 0.f};

    f32x4 acc[4][4];
#pragma unroll
    for (int i = 0; i < 4; ++i)
#pragma unroll
        for (int j = 0; j < 4; ++j) acc[i][j] = (f32x4){0.f, 0.f, 0.f, 0.f};

    for (int kt = 0; kt < 8; ++kt) {
        __syncthreads();
#pragma unroll
        for (int it = 0; it < 2; ++it) {
            GLDS16(asrc[it],      &A_[0][it * 2048 + wid * 512]);
            GLDS16(asrc[it] + 32, &A_[1][it * 2048 + wid * 512]);
            asrc[it] += 64;
        }
#pragma unroll
        for (int h = 0; h < 2; ++h)
#pragma unroll
            for (int j = 0; j < 2; ++j) {
                const int lp = lpb + j;
                const int l = kt * 64 + h * 32 + lp * 2;
                const float* vp = Vg + (size_t)l * 512 + dq * 4;
                float4 va = *reinterpret_cast<const float4*>(vp);
                float4 vb = *reinterpret_cast<const float4*>(vp + 512);
                const int lo = lp * 2;
                const int lblk = lo >> 3, lin = lo & 7;
                float av[4] = {va.x, va.y, va.z, va.w};
                float bv[4] = {vb.x, vb.y, vb.z, vb.w};
#pragma unroll
                for (int d = 0; d < 4; ++d) {
                    const int drow = dq * 4 + d;
                    const int ls = (lblk ^ ((drow >> 1) & 3)) * 8 + lin;
                    *reinterpret_cast<u32*>(&B_[h][drow * 32 + ls]) = cvtpk(av[d], bv[d]);
                    vs[d] += av[d] + bv[d];
                }
            }
        __syncthreads();
#pragma unroll
        for (int h = 0; h < 2; ++h) {
            bf16x8 a[4];
#pragma unroll
            for (int mf = 0; mf < 4; ++mf)
                a[mf] = *reinterpret_cast<const bf16x8*>(&A_[h][(wr * 64 + mf * 16 + l15) * 32 + koff]);
#pragma unroll
            for (int nf = 0; nf < 4; ++nf) {
                bf16x8 bb = *reinterpret_cast<const bf16x8*>(&B_[h][(wc * 64 + nf * 16 + l15) * 32 + koff]);
#pragma unroll
                for (int mf = 0; mf < 4; ++mf)
                    acc[mf][nf] = __builtin_amdgcn_mfma_f32_16x16x32_bf16(a[mf], bb, acc[mf][nf], 0, 0, 0);
            }
        }
    }
#pragma unroll
    for (int d = 0; d < 4; ++d) {
        vs[d] += __shfl_xor(vs[d], 1);
        vs[d] += __shfl_xor(vs[d], 2);
        vs[d] += __shfl_xor(vs[d], 4);
    }
    if (mt == 0 && (t & 7) == 0) {
        float4 w = make_float4(vs[0], vs[1], vs[2], vs[3]);
        *reinterpret_cast<float4*>(&vsump[(size_t)ch * 2048 + b * 512 + dt * 128 + dq * 4]) = w;
    }
#pragma unroll
    for (int mf = 0; mf < 4; ++mf)
#pragma unroll
        for (int r = 0; r < 4; ++r) {
            size_t oo = ((size_t)(ch * 4 + b) * 256 + mt * 128 + wr * 64 + mf * 16 + l4 * 4 + r) * 512
                        + dt * 128 + wc * 64;
#pragma unroll
            for (int nf = 0; nf < 4; ++nf)
                kvp[oo + nf * 16 + l15] = acc[mf][nf][r];
        }
}

// Vsum[b][d] = sum over 16 chunks of vsump[ch][b*512+d]
__global__ __launch_bounds__(256) void vsum_red(const float* __restrict__ vsump,
        float* __restrict__ Vsum) {
    const int o = blockIdx.x * 256 + threadIdx.x;   // 0..2047
    float s = 0.f;
#pragma unroll
    for (int c = 0; c < 16; ++c) s += vsump[(size_t)c * 2048 + o];
    Vsum[o] = s;
}

// reduce 16 chunks + KV_adj = g*KV + EPS*Vsum, split hi/lo, transpose -> KVt [b][d][m]
__global__ __launch_bounds__(256) void kv_fix(const float* __restrict__ kvp,
        const u32* __restrict__ bmax, const float* __restrict__ Vsum,
        u16* __restrict__ KVth, u16* __restrict__ KVtl) {
    const int dt = blockIdx.x & 7, mt = (blockIdx.x >> 3) & 3, b = blockIdx.x >> 5;
    const int m0 = mt * 64, d0 = dt * 64;
    __shared__ u16 Th[64][72], Tl[64][72];
    const int t = threadIdx.x, mloc = t >> 2, c0 = (t & 3) * 16;
    float s[16];
#pragma unroll
    for (int j = 0; j < 16; ++j) s[j] = 0.f;
    for (int c = 0; c < 16; ++c) {
        size_t base = ((size_t)(c * 4 + b) * 256 + m0 + mloc) * 512 + d0 + c0;
#pragma unroll
        for (int ii = 0; ii < 4; ++ii) {
            float4 v = *reinterpret_cast<const float4*>(&kvp[base + ii * 4]);
            s[ii * 4 + 0] += v.x; s[ii * 4 + 1] += v.y;
            s[ii * 4 + 2] += v.z; s[ii * 4 + 3] += v.w;
        }
    }
    const float g = expf(-odec(bmax[b]));
#pragma unroll
    for (int j = 0; j < 16; j += 2) {
        float v0 = g * s[j]     + EPS_ * Vsum[b * 512 + d0 + c0 + j];
        float v1 = g * s[j + 1] + EPS_ * Vsum[b * 512 + d0 + c0 + j + 1];
        u32 hw, lw; split_pk(v0, v1, hw, lw);
        *reinterpret_cast<u32*>(&Th[mloc][c0 + j]) = hw;
        *reinterpret_cast<u32*>(&Tl[mloc][c0 + j]) = lw;
    }
    __syncthreads();
    const int dloc = t >> 2, mc = (t & 3) * 16;
    size_t ob = ((size_t)(b * 512 + d0 + dloc)) * 256 + m0 + mc;
    u32 wh[8], wl[8];
#pragma unroll
    for (int j = 0; j < 8; ++j) {
        wh[j] = (u32)Th[mc + 2 * j][dloc] | ((u32)Th[mc + 2 * j + 1][dloc] << 16);
        wl[j] = (u32)Tl[mc + 2 * j][dloc] | ((u32)Tl[mc + 2 * j + 1][dloc] << 16);
    }
    reinterpret_cast<uint4*>(&KVth[ob])[0] = make_uint4(wh[0], wh[1], wh[2], wh[3]);
    reinterpret_cast<uint4*>(&KVth[ob])[1] = make_uint4(wh[4], wh[5], wh[6], wh[7]);
    reinterpret_cast<uint4*>(&KVtl[ob])[0] = make_uint4(wl[0], wl[1], wl[2], wl[3]);
    reinterpret_cast<uint4*>(&KVtl[ob])[1] = make_uint4(wl[4], wl[5], wl[6], wl[7]);
}

// Z[row] = 1/(dot(Qf_bf16, Ksum_true[b]) + eps)
__global__ __launch_bounds__(256) void z_kernel(const u16* __restrict__ QF,
        const float* __restrict__ KsumT, float* __restrict__ Z) {
    const int wid = threadIdx.x >> 6, lane = threadIdx.x & 63;
    const int row = blockIdx.x * 4 + wid;
    const int b = row >> 13;
    uint2 u = *reinterpret_cast<const uint2*>(&QF[(size_t)row * 256 + lane * 4]);
    float4 ks = *reinterpret_cast<const float4*>(&KsumT[b * 256 + lane * 4]);
    float s = bf2f((u16)(u.x & 0xffff)) * ks.x + bf2f((u16)(u.x >> 16)) * ks.y +
              bf2f((u16)(u.y & 0xffff)) * ks.z + bf2f((u16)(u.y >> 16)) * ks.w;
#pragma unroll
    for (int off = 1; off < 64; off <<= 1) s += __shfl_xor(s, off);
    if (lane == 0) Z[row] = 1.f / (s + EPS_);
}

// ---------------------------------------------------------------------------
// out GEMM, BK=64 (4 K-steps). Tile 128x128, 256 thr / 4 waves, LDS 48 KB,
// grid 1024. (R17-proven form.)
// ---------------------------------------------------------------------------
__global__ __launch_bounds__(256) void out_mfma(
        const u16* __restrict__ QF, const u16* __restrict__ KVth,
        const float* __restrict__ Z, float* __restrict__ out) {
    int o = (blockIdx.x & 7) * 128 + (blockIdx.x >> 3);
    const int dt = o & 3, rt = o >> 2;
    const int row0 = rt * 128, b = row0 >> 13;
    const u16* Ag = QF + (size_t)row0 * 256;
    const u16* Bh_g = KVth + ((size_t)(b * 512 + dt * 128)) * 256;
    __shared__ __align__(16) u16 A_[2][128 * 32], Bh_[2][128 * 32], Bl_[2][128 * 32];
    const int t = threadIdx.x, lane = t & 63;
    const int wid = t >> 6, wr = wid >> 1, wc = wid & 1;
    const int l15 = lane & 15, l4 = lane >> 4;
    const int koff = (l4 ^ ((l15 >> 1) & 3)) * 8;
    const u16* asrc[2];
    const u16* bhsrc[2];
#pragma unroll
    for (int it = 0; it < 2; ++it) {
        const int row = it * 64 + wid * 16 + (lane >> 2);
        const int swz = ((lane & 3) ^ ((row >> 1) & 3)) * 8;
        asrc[it]  = Ag + (size_t)row * 256 + swz;
        bhsrc[it] = Bh_g + (size_t)row * 256 + swz;
    }
    f32x4 acc[4][4];
#pragma unroll
    for (int i = 0; i < 4; ++i)
#pragma unroll
        for (int j = 0; j < 4; ++j) acc[i][j] = (f32x4){0.f, 0.f, 0.f, 0.f};

    for (int kt = 0; kt < 4; ++kt) {
        __syncthreads();
#pragma unroll
        for (int it = 0; it < 2; ++it) {
            GLDS16(asrc[it],                  &A_[0][it * 2048 + wid * 512]);
            GLDS16(asrc[it] + 32,             &A_[1][it * 2048 + wid * 512]);
            GLDS16(bhsrc[it],                 &Bh_[0][it * 2048 + wid * 512]);
            GLDS16(bhsrc[it] + 32,            &Bh_[1][it * 2048 + wid * 512]);
            GLDS16(bhsrc[it] + KVL_OFF_,      &Bl_[0][it * 2048 + wid * 512]);
            GLDS16(bhsrc[it] + 32 + KVL_OFF_, &Bl_[1][it * 2048 + wid * 512]);
            asrc[it] += 64; bhsrc[it] += 64;
        }
        __syncthreads();
#pragma unroll
        for (int h = 0; h < 2; ++h) {
            bf16x8 a[4];
#pragma unroll
            for (int mf = 0; mf < 4; ++mf)
                a[mf] = *reinterpret_cast<const bf16x8*>(&A_[h][(wr * 64 + mf * 16 + l15) * 32 + koff]);
#pragma unroll
            for (int nf = 0; nf < 4; ++nf) {
                const int r = (wc * 64 + nf * 16 + l15) * 32 + koff;
                bf16x8 bh = *reinterpret_cast<const bf16x8*>(&Bh_[h][r]);
                bf16x8 bl = *reinterpret_cast<const bf16x8*>(&Bl_[h][r]);
#pragma unroll
                for (int mf = 0; mf < 4; ++mf) {
                    acc[mf][nf] = __builtin_amdgcn_mfma_f32_16x16x32_bf16(a[mf], bh, acc[mf][nf], 0, 0, 0);
                    acc[mf][nf] = __builtin_amdgcn_mfma_f32_16x16x32_bf16(a[mf], bl, acc[mf][nf], 0, 0, 0);
                }
            }
        }
    }
#pragma unroll
    for (int mf = 0; mf < 4; ++mf)
#pragma unroll
        for (int r = 0; r < 4; ++r) {
            const int row = row0 + wr * 64 + mf * 16 + l4 * 4 + r;
            const float z = Z[row];
#pragma unroll
            for (int nf = 0; nf < 4; ++nf)
                out[(size_t)row * 512 + dt * 128 + wc * 64 + nf * 16 + l15] = acc[mf][nf][r] * z;
        }
}

extern "C" void kernel_launch(void* const* d_in, const int* in_sizes, int n_in,
                              void* d_out, int out_size, void* d_ws, size_t ws_size,
                              hipStream_t stream) {
    const float* Q = (const float*)d_in[0];
    const float* K = (const float*)d_in[1];
    const float* V = (const float*)d_in[2];
    const float* P = (const float*)d_in[3];
    float* out = (float*)d_out;
    char* ws = (char*)d_ws;

    u16*   QF    = (u16*)(ws + 0);             // 16 MiB
    u16*   KfT   = (u16*)(ws + 16777216);      // 16 MiB
    float* kvp   = (float*)(ws + 33554432);    // 32 MiB
    u16*   KVth  = (u16*)(ws + 67108864);      // 1 MiB
    u16*   KVtl  = (u16*)(ws + 68157440);      // 1 MiB (= KVth + 524288 elems)
    u16*   PH    = (u16*)(ws + 69206016);      // 256 KiB
    u16*   PL    = (u16*)(ws + 69468160);      // 256 KiB (= PH + 131072 elems)
    float* ksump = (float*)(ws + 69730304);    // 512 KiB
    float* vsump = (float*)(ws + 70254592);    // 128 KiB (16 ch x 2048)
    float* KsumT = (float*)(ws + 70385664);    // 4 KiB
    float* Vsum  = (float*)(ws + 70389760);    // 8 KiB
    float* Zbuf  = (float*)(ws + 70397952);    // 128 KiB
    u32*   bmax  = (u32*)(ws + 70529024);      // 16 B

    split_p<<<256, 256, 0, stream>>>(P, PH, PL, bmax);
    dash_all<<<1024, 256, 0, stream>>>(Q, K, PH, QF, KfT, ksump, bmax);
    ksum_red<<<256, 256, 0, stream>>>(ksump, bmax, KsumT);
    kv_mfma<<<512, 256, 0, stream>>>(KfT, V, kvp, vsump);
    vsum_red<<<8, 256, 0, stream>>>(vsump, Vsum);
    kv_fix<<<128, 256, 0, stream>>>(kvp, bmax, Vsum, KVth, KVtl);
    z_kernel<<<8192, 256, 0, stream>>>(QF, KsumT, Zbuf);
    out_mfma<<<1024, 256, 0, stream>>>(QF, KVth, Zbuf, out);
}